// Round 3
// baseline (440.428 us; speedup 1.0000x reference)
//
#include <hip/hip_runtime.h>
#include <math.h>

#define N_NODES 50000
#define N_EDGES 1200000
#define BATCH   64
#define D       64
#define EPS     1e-12f
#define PBLK    128   // pool partial blocks

// ---------------------------------------------------------------------------
// CSR row offsets from sorted edge_row: row_start[r] = lower_bound(edge_row, r)
// ---------------------------------------------------------------------------
__global__ void k_rowstart(const int* __restrict__ edge_row, int* __restrict__ row_start) {
    int r = blockIdx.x * blockDim.x + threadIdx.x;
    if (r > N_NODES) return;
    int lo = 0, hi = N_EDGES;
    while (lo < hi) {
        int mid = (lo + hi) >> 1;
        if (edge_row[mid] < r) lo = mid + 1; else hi = mid;
    }
    row_start[r] = lo;
}

// ---------------------------------------------------------------------------
// Fused weights, interleaved: MM[k][j][0] = (W2@Wl_top)[k][j], MM[k][j][1] = (W3@Wl_bot)[k][j]
// ---------------------------------------------------------------------------
__global__ void k_fuse(const float* __restrict__ W2, const float* __restrict__ W3,
                       const float* __restrict__ Wl, float* __restrict__ MM) {
    int k = blockIdx.x, j = threadIdx.x;
    float a2 = 0.f, a3 = 0.f;
    for (int t = 0; t < D; ++t) {
        a2 += W2[k*D + t] * Wl[t*D + j];
        a3 += W3[k*D + t] * Wl[(D + t)*D + j];
    }
    MM[k*2*D + 2*j]     = a2;
    MM[k*2*D + 2*j + 1] = a3;
}

__device__ __forceinline__ float lane_bcast(float v, int k) {
    return __uint_as_float(__builtin_amdgcn_readlane(__float_as_uint(v), k));
}

__device__ __forceinline__ float wave_l2norm(float v) {
    float ss = v * v;
    #pragma unroll
    for (int off = 32; off; off >>= 1) ss += __shfl_xor(ss, off);
    return sqrtf(ss);
}

// ---------------------------------------------------------------------------
// h0 = l2norm(relu(X @ W1)); nodes -> B0 (ws), batch seeds -> HS (d_out)
// ---------------------------------------------------------------------------
__global__ void __launch_bounds__(256) k_init(const float* __restrict__ X,
                                              const float* __restrict__ Xs,
                                              const float* __restrict__ W1,
                                              float* __restrict__ B0,
                                              float* __restrict__ HS) {
    int row = blockIdx.x * 4 + (threadIdx.x >> 6);
    int j   = threadIdx.x & 63;
    if (row >= N_NODES + BATCH) return;
    float x0, x1; float* out;
    if (row < N_NODES) {
        x0 = X[row*2]; x1 = X[row*2 + 1]; out = B0 + (size_t)row * D;
    } else {
        int r = row - N_NODES;
        x0 = Xs[r*2]; x1 = Xs[r*2 + 1]; out = HS + (size_t)r * D;
    }
    float v = fmaxf(fmaf(x0, W1[j], x1 * W1[D + j]), 0.f);
    float n = wave_l2norm(v);
    out[j] = v / fmaxf(n, EPS);
}

// ---------------------------------------------------------------------------
// Fused iteration (nodes). One wave per row.
// Gather phase: float4 per lane, 4 edges per load instruction, 8-deep unroll
//   lane l: p = l&15 owns dims 4p..4p+3, q = l>>4 selects edge within quad.
// Dense phase: lane l owns output dim l; M2/M3 interleaved in LDS (ds_read_b64).
// ---------------------------------------------------------------------------
__global__ void __launch_bounds__(512, 4) k_iter(const int* __restrict__ edge_col,
                                                 const int* __restrict__ row_start,
                                                 const float* __restrict__ Hc,
                                                 float* __restrict__ Hn,
                                                 const float* __restrict__ MM,
                                                 const float* __restrict__ bl) {
    __shared__ float sMM[2 * D * D];
    int t = threadIdx.x;
    for (int i = t; i < 2 * D * D; i += 512) sMM[i] = MM[i];
    __syncthreads();
    int row = blockIdx.x * 8 + (t >> 6);   // grid is exactly 50000/8 = 6250
    int l = t & 63;
    int p = l & 15, q = l >> 4;

    int s = __builtin_amdgcn_readfirstlane(row_start[row]);
    int e = __builtin_amdgcn_readfirstlane(row_start[row + 1]);

    float hv = Hc[(size_t)row * D + l];

    const float* __restrict__ Hb = Hc + p * 4;
    float4 acc = make_float4(0.f, 0.f, 0.f, 0.f);
    int i = s;
    for (; i + 32 <= e; i += 32) {
        int cc[8];
        #pragma unroll
        for (int u = 0; u < 8; ++u) cc[u] = edge_col[i + 4*u + q];
        float4 vv[8];
        #pragma unroll
        for (int u = 0; u < 8; ++u) vv[u] = *(const float4*)(Hb + (size_t)cc[u] * D);
        #pragma unroll
        for (int u = 0; u < 8; ++u) {
            acc.x += vv[u].x; acc.y += vv[u].y; acc.z += vv[u].z; acc.w += vv[u].w;
        }
    }
    for (; i + 4 <= e; i += 4) {
        int c = edge_col[i + q];
        float4 v = *(const float4*)(Hb + (size_t)c * D);
        acc.x += v.x; acc.y += v.y; acc.z += v.z; acc.w += v.w;
    }
    int rem = e - i;
    if (q < rem) {
        int c = edge_col[i + q];
        float4 v = *(const float4*)(Hb + (size_t)c * D);
        acc.x += v.x; acc.y += v.y; acc.z += v.z; acc.w += v.w;
    }
    // fold the 4 edge-subgroups (q) together
    acc.x += __shfl_xor(acc.x, 16); acc.y += __shfl_xor(acc.y, 16);
    acc.z += __shfl_xor(acc.z, 16); acc.w += __shfl_xor(acc.w, 16);
    acc.x += __shfl_xor(acc.x, 32); acc.y += __shfl_xor(acc.y, 32);
    acc.z += __shfl_xor(acc.z, 32); acc.w += __shfl_xor(acc.w, 32);
    // redistribute: lane l wants dim l = component (l&3) of lane (l>>2)
    int src = l >> 2;
    float t0 = __shfl(acc.x, src), t1 = __shfl(acc.y, src);
    float t2 = __shfl(acc.z, src), t3 = __shfl(acc.w, src);
    int m = l & 3;
    float gv = (m == 0) ? t0 : (m == 1) ? t1 : (m == 2) ? t2 : t3;

    float a2 = 0.f, a3 = bl[l];
    #pragma unroll
    for (int k = 0; k < D; ++k) {
        float hk = lane_bcast(hv, k);
        float gk = lane_bcast(gv, k);
        float2 mm = *(const float2*)&sMM[k * 2 * D + 2 * l];
        a2 = fmaf(hk, mm.x, a2);
        a3 = fmaf(gk, mm.y, a3);
    }
    float v = fmaxf(a2 + a3, 0.f);
    float n = wave_l2norm(v);
    Hn[(size_t)row * D + l] = v / fmaxf(n, EPS);
}

// ---------------------------------------------------------------------------
// Batch pool, phase 1: per-block LDS accumulation -> private partials (no
// global atomics, no memset needed: partials fully overwritten each call).
// ---------------------------------------------------------------------------
__global__ void __launch_bounds__(512) k_pool(const int* __restrict__ batch_assign,
                                              const float* __restrict__ H,
                                              float* __restrict__ partials) {
    __shared__ float acc[BATCH * D];
    int t = threadIdx.x;
    for (int i = t; i < BATCH * D; i += 512) acc[i] = 0.f;
    __syncthreads();
    int lane = t & 63;
    int wave = blockIdx.x * 8 + (t >> 6);
    const int nwaves = PBLK * 8;
    for (int n = wave; n < N_NODES; n += nwaves) {
        int b = batch_assign[n];
        atomicAdd(&acc[b * D + lane], H[(size_t)n * D + lane]);
    }
    __syncthreads();
    float* out = partials + (size_t)blockIdx.x * (BATCH * D);
    for (int i = t; i < BATCH * D; i += 512) out[i] = acc[i];
}

// ---------------------------------------------------------------------------
// hs update: reduce pool partials in-register, then GEMV + relu + l2norm.
// ---------------------------------------------------------------------------
__global__ void __launch_bounds__(256) k_hs(float* __restrict__ HS,
                                            const float* __restrict__ partials,
                                            const float* __restrict__ MM,
                                            const float* __restrict__ bl) {
    __shared__ float sMM[2 * D * D];
    int t = threadIdx.x;
    for (int i = t; i < 2 * D * D; i += 256) sMM[i] = MM[i];
    __syncthreads();
    int row = blockIdx.x * 4 + (t >> 6);   // grid 16 -> rows 0..63
    int j = t & 63;
    float g0 = 0.f, g1 = 0.f, g2 = 0.f, g3 = 0.f;
    const float* base = partials + row * D + j;
    #pragma unroll 4
    for (int pb = 0; pb < PBLK; pb += 4) {
        g0 += base[(size_t)(pb + 0) * (BATCH * D)];
        g1 += base[(size_t)(pb + 1) * (BATCH * D)];
        g2 += base[(size_t)(pb + 2) * (BATCH * D)];
        g3 += base[(size_t)(pb + 3) * (BATCH * D)];
    }
    float gv = (g0 + g1) + (g2 + g3);
    float hv = HS[(size_t)row * D + j];
    float a2 = 0.f, a3 = bl[j];
    #pragma unroll
    for (int k = 0; k < D; ++k) {
        float hk = lane_bcast(hv, k);
        float gk = lane_bcast(gv, k);
        float2 mm = *(const float2*)&sMM[k * 2 * D + 2 * j];
        a2 = fmaf(hk, mm.x, a2);
        a3 = fmaf(gk, mm.y, a3);
    }
    float v = fmaxf(a2 + a3, 0.f);
    float n = wave_l2norm(v);
    HS[(size_t)row * D + j] = v / fmaxf(n, EPS);
}

// ---------------------------------------------------------------------------
extern "C" void kernel_launch(void* const* d_in, const int* in_sizes, int n_in,
                              void* d_out, int out_size, void* d_ws, size_t ws_size,
                              hipStream_t stream) {
    const int*   edge_row = (const int*)  d_in[0];
    const int*   edge_col = (const int*)  d_in[1];
    const int*   batch    = (const int*)  d_in[2];
    const float* X        = (const float*)d_in[3];
    const float* Xs       = (const float*)d_in[4];
    const float* W1       = (const float*)d_in[5];
    const float* W2       = (const float*)d_in[6];
    const float* W3       = (const float*)d_in[7];
    const float* Wl       = (const float*)d_in[8];
    const float* bl       = (const float*)d_in[9];

    float* H  = (float*)d_out;                        // final node embeddings
    float* HS = (float*)d_out + (size_t)N_NODES * D;  // hs (updated in place)

    // workspace: B0, B1 ping-pong node buffers + partials + MM + row_start
    float* B0       = (float*)d_ws;                       // N_NODES*D
    float* B1       = B0 + (size_t)N_NODES * D;           // N_NODES*D
    float* partials = B1 + (size_t)N_NODES * D;           // PBLK*BATCH*D (2 MB)
    float* MM       = partials + (size_t)PBLK * BATCH * D;// 2*D*D
    int*   row_start = (int*)(MM + 2 * D * D);            // N_NODES+1

    k_rowstart<<<(N_NODES + 256) / 256, 256, 0, stream>>>(edge_row, row_start);
    k_fuse<<<D, D, 0, stream>>>(W2, W3, Wl, MM);
    k_init<<<(N_NODES + BATCH + 3) / 4, 256, 0, stream>>>(X, Xs, W1, B0, HS);

    const int nblk = N_NODES / 8;   // 6250, exact

    // iter 1: B0 -> B1
    k_iter<<<nblk, 512, 0, stream>>>(edge_col, row_start, B0, B1, MM, bl);
    k_pool<<<PBLK, 512, 0, stream>>>(batch, B0, partials);
    k_hs<<<16, 256, 0, stream>>>(HS, partials, MM, bl);

    // iter 2: B1 -> B0
    k_iter<<<nblk, 512, 0, stream>>>(edge_col, row_start, B1, B0, MM, bl);
    k_pool<<<PBLK, 512, 0, stream>>>(batch, B1, partials);
    k_hs<<<16, 256, 0, stream>>>(HS, partials, MM, bl);

    // iter 3: B0 -> H (d_out)
    k_iter<<<nblk, 512, 0, stream>>>(edge_col, row_start, B0, H, MM, bl);
    k_pool<<<PBLK, 512, 0, stream>>>(batch, B0, partials);
    k_hs<<<16, 256, 0, stream>>>(HS, partials, MM, bl);
}

// Round 5
// 301.844 us; speedup vs baseline: 1.4591x; 1.4591x over previous
//
#include <hip/hip_runtime.h>
#include <math.h>

#define N_NODES 50000
#define N_EDGES 1200000
#define BATCH   64
#define D       64
#define EPS     1e-12f
#define NCOPY   64   // replicated pool buffers (contention spread)

// ---------------------------------------------------------------------------
// CSR row offsets from sorted edge_row + zero both pool buffers
// ---------------------------------------------------------------------------
__global__ void k_rowstart(const int* __restrict__ edge_row, int* __restrict__ row_start,
                           float* __restrict__ pools /* 2*NCOPY*BATCH*D */) {
    int tid = blockIdx.x * blockDim.x + threadIdx.x;
    int nthr = gridDim.x * blockDim.x;
    for (int i = tid; i < 2 * NCOPY * BATCH * D; i += nthr) pools[i] = 0.f;
    if (tid > N_NODES) return;
    int lo = 0, hi = N_EDGES;
    while (lo < hi) {
        int mid = (lo + hi) >> 1;
        if (edge_row[mid] < tid) lo = mid + 1; else hi = mid;
    }
    row_start[tid] = lo;
}

// ---------------------------------------------------------------------------
// Fused weights, interleaved: MM[k][j][0]=(W2@Wl_top)[k][j], MM[k][j][1]=(W3@Wl_bot)[k][j]
// ---------------------------------------------------------------------------
__global__ void k_fuse(const float* __restrict__ W2, const float* __restrict__ W3,
                       const float* __restrict__ Wl, float* __restrict__ MM) {
    int k = blockIdx.x, j = threadIdx.x;
    float a2 = 0.f, a3 = 0.f;
    for (int t = 0; t < D; ++t) {
        a2 += W2[k*D + t] * Wl[t*D + j];
        a3 += W3[k*D + t] * Wl[(D + t)*D + j];
    }
    MM[k*2*D + 2*j]     = a2;
    MM[k*2*D + 2*j + 1] = a3;
}

__device__ __forceinline__ float lane_bcast(float v, int k) {
    return __uint_as_float(__builtin_amdgcn_readlane(__float_as_uint(v), k));
}

__device__ __forceinline__ float wave_l2norm(float v) {
    float ss = v * v;
    #pragma unroll
    for (int off = 32; off; off >>= 1) ss += __shfl_xor(ss, off);
    return sqrtf(ss);
}

// ---------------------------------------------------------------------------
// h0 = l2norm(relu(X @ W1)); nodes -> B0 (+pool into P0), batch seeds -> HS
// ---------------------------------------------------------------------------
__global__ void __launch_bounds__(256) k_init(const float* __restrict__ X,
                                              const float* __restrict__ Xs,
                                              const float* __restrict__ W1,
                                              float* __restrict__ B0,
                                              float* __restrict__ HS,
                                              const int* __restrict__ batch,
                                              float* __restrict__ P0) {
    int row = blockIdx.x * 4 + (threadIdx.x >> 6);
    int j   = threadIdx.x & 63;
    if (row >= N_NODES + BATCH) return;
    float x0, x1; float* out;
    bool is_node = (row < N_NODES);
    if (is_node) {
        x0 = X[row*2]; x1 = X[row*2 + 1]; out = B0 + (size_t)row * D;
    } else {
        int r = row - N_NODES;
        x0 = Xs[r*2]; x1 = Xs[r*2 + 1]; out = HS + (size_t)r * D;
    }
    float v = fmaxf(fmaf(x0, W1[j], x1 * W1[D + j]), 0.f);
    float n = wave_l2norm(v);
    float val = v / fmaxf(n, EPS);
    out[j] = val;
    if (is_node) {
        int b = __builtin_amdgcn_readfirstlane(batch[row]);
        atomicAdd(&P0[(blockIdx.x & (NCOPY - 1)) * (BATCH * D) + b * D + j], val);
    }
}

// ---------------------------------------------------------------------------
// Fused iteration (nodes). One wave per row, lane = dim everywhere.
// Gather: load <=64 edge cols in one vector load; readlane -> SGPR base ->
//   saddr-form 256B row loads, 16 independent per unrolled batch. Padding
//   gathers row 0 and is subtracted (branch-free).
// Dense: lane l owns output dim l; MM interleaved in LDS (ds_read_b64).
// Epilogue: producer-side pool of the OUTPUT row into Pout (64 replicas).
// ---------------------------------------------------------------------------
__global__ void __launch_bounds__(512, 4) k_iter(const int* __restrict__ edge_col,
                                                 const int* __restrict__ row_start,
                                                 const float* __restrict__ Hc,
                                                 float* __restrict__ Hn,
                                                 const float* __restrict__ MM,
                                                 const float* __restrict__ bl,
                                                 const int* __restrict__ batch,
                                                 float* __restrict__ Pout) {
    __shared__ float sMM[2 * D * D];
    int t = threadIdx.x;
    for (int i = t; i < 2 * D * D; i += 512) sMM[i] = MM[i];
    __syncthreads();
    int row = blockIdx.x * 8 + (t >> 6);   // grid exactly 50000/8 = 6250
    int l = t & 63;

    int s = __builtin_amdgcn_readfirstlane(row_start[row]);
    int e = __builtin_amdgcn_readfirstlane(row_start[row + 1]);

    float hv = Hc[(size_t)row * D + l];
    const float* __restrict__ Hl = Hc + l;

    float acc = 0.f;
    int pad = 0;
    for (int base = s; base < e; base += 64) {
        int cw = e - base; if (cw > 64) cw = 64;
        int col = 0;
        if (l < cw) col = edge_col[base + l];
        int nb = (cw + 15) >> 4;
        pad += (nb << 4) - cw;
        for (int b = 0; b < nb; ++b) {
            int o = b << 4;
            #pragma unroll
            for (int u = 0; u < 16; ++u) {
                int c = __builtin_amdgcn_readlane(col, o + u);
                acc += Hl[(size_t)c * D];
            }
        }
    }
    acc -= (float)pad * Hl[0];
    float gv = acc;

    float a2 = 0.f, a3 = bl[l];
    #pragma unroll
    for (int k = 0; k < D; ++k) {
        float hk = lane_bcast(hv, k);
        float gk = lane_bcast(gv, k);
        float2 mm = *(const float2*)&sMM[k * 2 * D + 2 * l];
        a2 = fmaf(hk, mm.x, a2);
        a3 = fmaf(gk, mm.y, a3);
    }
    float v = fmaxf(a2 + a3, 0.f);
    float n = wave_l2norm(v);
    float val = v / fmaxf(n, EPS);
    Hn[(size_t)row * D + l] = val;

    if (Pout) {
        int b = __builtin_amdgcn_readfirstlane(batch[row]);
        atomicAdd(&Pout[(blockIdx.x & (NCOPY - 1)) * (BATCH * D) + b * D + l], val);
    }
}

// ---------------------------------------------------------------------------
// hs update: sum the NCOPY pool replicas (re-zeroing them for reuse), then
// GEMV + relu + l2norm. grid 16 x 256 = one thread per (row, dim).
// ---------------------------------------------------------------------------
__global__ void __launch_bounds__(256) k_hs(float* __restrict__ HS,
                                            float* __restrict__ P,
                                            const float* __restrict__ MM,
                                            const float* __restrict__ bl) {
    __shared__ float sMM[2 * D * D];
    int t = threadIdx.x;
    for (int i = t; i < 2 * D * D; i += 256) sMM[i] = MM[i];
    __syncthreads();
    int row = blockIdx.x * 4 + (t >> 6);   // rows 0..63
    int j = t & 63;
    float* base = P + row * D + j;
    float g0 = 0.f, g1 = 0.f, g2 = 0.f, g3 = 0.f;
    #pragma unroll 8
    for (int c = 0; c < NCOPY; c += 4) {
        float v0 = base[(size_t)(c + 0) * (BATCH * D)];
        float v1 = base[(size_t)(c + 1) * (BATCH * D)];
        float v2 = base[(size_t)(c + 2) * (BATCH * D)];
        float v3 = base[(size_t)(c + 3) * (BATCH * D)];
        base[(size_t)(c + 0) * (BATCH * D)] = 0.f;
        base[(size_t)(c + 1) * (BATCH * D)] = 0.f;
        base[(size_t)(c + 2) * (BATCH * D)] = 0.f;
        base[(size_t)(c + 3) * (BATCH * D)] = 0.f;
        g0 += v0; g1 += v1; g2 += v2; g3 += v3;
    }
    float gv = (g0 + g1) + (g2 + g3);
    float hv = HS[(size_t)row * D + j];
    float a2 = 0.f, a3 = bl[j];
    #pragma unroll
    for (int k = 0; k < D; ++k) {
        float hk = lane_bcast(hv, k);
        float gk = lane_bcast(gv, k);
        float2 mm = *(const float2*)&sMM[k * 2 * D + 2 * j];
        a2 = fmaf(hk, mm.x, a2);
        a3 = fmaf(gk, mm.y, a3);
    }
    float v = fmaxf(a2 + a3, 0.f);
    float n = wave_l2norm(v);
    HS[(size_t)row * D + j] = v / fmaxf(n, EPS);
}

// ---------------------------------------------------------------------------
extern "C" void kernel_launch(void* const* d_in, const int* in_sizes, int n_in,
                              void* d_out, int out_size, void* d_ws, size_t ws_size,
                              hipStream_t stream) {
    const int*   edge_row = (const int*)  d_in[0];
    const int*   edge_col = (const int*)  d_in[1];
    const int*   batch    = (const int*)  d_in[2];
    const float* X        = (const float*)d_in[3];
    const float* Xs       = (const float*)d_in[4];
    const float* W1       = (const float*)d_in[5];
    const float* W2       = (const float*)d_in[6];
    const float* W3       = (const float*)d_in[7];
    const float* Wl       = (const float*)d_in[8];
    const float* bl       = (const float*)d_in[9];

    float* H  = (float*)d_out;                        // final node embeddings
    float* HS = (float*)d_out + (size_t)N_NODES * D;  // hs (updated in place)

    // workspace: B0, B1 ping-pong + 2 pool replica-sets + MM + row_start
    float* B0  = (float*)d_ws;                          // N_NODES*D
    float* B1  = B0 + (size_t)N_NODES * D;              // N_NODES*D
    float* PA  = B1 + (size_t)N_NODES * D;              // NCOPY*BATCH*D (1 MB)
    float* PB  = PA + (size_t)NCOPY * BATCH * D;        // NCOPY*BATCH*D (1 MB)
    float* MM  = PB + (size_t)NCOPY * BATCH * D;        // 2*D*D
    int*   row_start = (int*)(MM + 2 * D * D);          // N_NODES+1

    const int nblk = N_NODES / 8;   // 6250, exact

    k_rowstart<<<(N_NODES + 256) / 256, 256, 0, stream>>>(edge_row, row_start, PA);
    k_fuse<<<D, D, 0, stream>>>(W2, W3, Wl, MM);
    k_init<<<(N_NODES + BATCH + 3) / 4, 256, 0, stream>>>(X, Xs, W1, B0, HS, batch, PA);

    // iter 1: h0(B0) -> h1(B1), pool h1 -> PB ; hs uses pool(h0)=PA
    k_iter<<<nblk, 512, 0, stream>>>(edge_col, row_start, B0, B1, MM, bl, batch, PB);
    k_hs<<<16, 256, 0, stream>>>(HS, PA, MM, bl);   // reads+zeroes PA

    // iter 2: h1(B1) -> h2(B0), pool h2 -> PA ; hs uses pool(h1)=PB
    k_iter<<<nblk, 512, 0, stream>>>(edge_col, row_start, B1, B0, MM, bl, batch, PA);
    k_hs<<<16, 256, 0, stream>>>(HS, PB, MM, bl);   // reads+zeroes PB

    // iter 3: h2(B0) -> h3(H, d_out), no pool ; hs uses pool(h2)=PA
    k_iter<<<nblk, 512, 0, stream>>>(edge_col, row_start, B0, H, MM, bl, batch, nullptr);
    k_hs<<<16, 256, 0, stream>>>(HS, PA, MM, bl);
}

// Round 6
// 281.689 us; speedup vs baseline: 1.5635x; 1.0715x over previous
//
#include <hip/hip_runtime.h>
#include <math.h>

#define N_NODES 50000
#define N_EDGES 1200000
#define BATCH   64
#define D       64
#define EPS     1e-12f
#define NCOPY   64          // replicated pool buffers
#define NODE_BLOCKS 3125    // 16 rows per 512-thread block (8 waves x 2 rows)
#define HS_BLOCKS   4       // 4 blocks x 16 rows = 64 hs rows
#define ITER_GRID  (NODE_BLOCKS + HS_BLOCKS)

__device__ __forceinline__ int rfl(int v) { return __builtin_amdgcn_readfirstlane(v); }

// ---------------------------------------------------------------------------
// Prologue: CSR row offsets (binary search on sorted edge_row) + zero both
// pool replica sets (ws is re-poisoned before every call) + fused weights.
// Blocks 0..97: rowstart + pool zero. Block 98: MM4.
// MM4 layout (float4, kk=0..31, j=0..63): {M2[2kk][j], M3[2kk][j], M2[2kk+1][j], M3[2kk+1][j]}
// ---------------------------------------------------------------------------
__global__ void __launch_bounds__(512) k_prep(const int* __restrict__ edge_row,
                                              int* __restrict__ row_start,
                                              float* __restrict__ pools,
                                              const float* __restrict__ W2,
                                              const float* __restrict__ W3,
                                              const float* __restrict__ Wl,
                                              float* __restrict__ MM4) {
    if (blockIdx.x < 98) {
        int tid = blockIdx.x * 512 + threadIdx.x;
        for (int i = tid; i < 2 * NCOPY * BATCH * D; i += 98 * 512) pools[i] = 0.f;
        if (tid > N_NODES) return;
        int lo = 0, hi = N_EDGES;
        while (lo < hi) {
            int mid = (lo + hi) >> 1;
            if (edge_row[mid] < tid) lo = mid + 1; else hi = mid;
        }
        row_start[tid] = lo;
    } else {
        for (int p = threadIdx.x; p < D * D; p += 512) {
            int k = p >> 6, j = p & 63;
            float a2 = 0.f, a3 = 0.f;
            for (int q = 0; q < D; ++q) {
                a2 += W2[k*D + q] * Wl[q*D + j];
                a3 += W3[k*D + q] * Wl[(D + q)*D + j];
            }
            MM4[(k >> 1) * D * 4 + j * 4 + (k & 1) * 2 + 0] = a2;
            MM4[(k >> 1) * D * 4 + j * 4 + (k & 1) * 2 + 1] = a3;
        }
    }
}

__device__ __forceinline__ float wave_l2norm(float v) {
    float ss = v * v;
    #pragma unroll
    for (int off = 32; off; off >>= 1) ss += __shfl_xor(ss, off);
    return ss;
}

// ---------------------------------------------------------------------------
// h0 = l2norm(relu(X @ W1)); nodes -> B0 (+pool into PA), batch seeds -> HS
// ---------------------------------------------------------------------------
__global__ void __launch_bounds__(256) k_init(const float* __restrict__ X,
                                              const float* __restrict__ Xs,
                                              const float* __restrict__ W1,
                                              float* __restrict__ B0,
                                              float* __restrict__ HS,
                                              const int* __restrict__ batch,
                                              float* __restrict__ P0) {
    int row = blockIdx.x * 4 + (threadIdx.x >> 6);
    int j   = threadIdx.x & 63;
    if (row >= N_NODES + BATCH) return;
    float x0, x1; float* out;
    bool is_node = (row < N_NODES);
    if (is_node) {
        x0 = X[row*2]; x1 = X[row*2 + 1]; out = B0 + (size_t)row * D;
    } else {
        int r = row - N_NODES;
        x0 = Xs[r*2]; x1 = Xs[r*2 + 1]; out = HS + (size_t)r * D;
    }
    float v = fmaxf(fmaf(x0, W1[j], x1 * W1[D + j]), 0.f);
    float n = sqrtf(wave_l2norm(v));
    float val = v / fmaxf(n, EPS);
    out[j] = val;
    if (is_node) {
        int b = rfl(batch[row]);
        atomicAdd(&P0[(blockIdx.x & (NCOPY - 1)) * (BATCH * D) + b * D + j], val);
    }
}

// ---------------------------------------------------------------------------
// Fused iteration. Blocks < NODE_BLOCKS: one wave = 2 adjacent node rows
// (their CSR edge ranges are contiguous -> one index load + one gather
// stream with wave-uniform A/B routing + one wait). Blocks >= NODE_BLOCKS:
// hs update (gv = pool-replica reduce of previous h, re-zeroing replicas).
// Dense phase shared: LDS-broadcast GEMV, no readlanes, MM in float4 k-pairs.
// ---------------------------------------------------------------------------
__global__ void __launch_bounds__(512, 8) k_iter(const int* __restrict__ edge_col,
                                                 const int* __restrict__ row_start,
                                                 const float* __restrict__ Hc,
                                                 float* __restrict__ Hn,
                                                 const float* __restrict__ MM4,
                                                 const float* __restrict__ bl,
                                                 const int* __restrict__ batch,
                                                 float* __restrict__ Pout,
                                                 float* __restrict__ HSrw,
                                                 float* __restrict__ Pin) {
    __shared__ float4 sMM[32 * 64];   // 32 KB
    __shared__ float4 sHG[8 * 64];    // 8 KB
    int t = threadIdx.x;
    const float4* gMM = (const float4*)MM4;
    for (int i = t; i < 32 * 64; i += 512) sMM[i] = gMM[i];
    __syncthreads();
    int w = t >> 6, l = t & 63;
    bool is_node = (blockIdx.x < NODE_BLOCKS);
    int rA, rB;
    float hvA, hvB, gvA, gvB;

    if (is_node) {
        int pr = blockIdx.x * 8 + w;       // pair index 0..24999
        rA = 2 * pr; rB = rA + 1;
        int sA = rfl(row_start[rA]);
        int eA = rfl(row_start[rB]);
        int eB = rfl(row_start[rB + 1]);
        hvA = Hc[(size_t)rA * D + l];
        hvB = Hc[(size_t)rB * D + l];
        float aA = 0.f, aB = 0.f;
        int pad = 0;
        for (int base = sA; base < eB; ) {
            int cw = eB - base; if (cw > 64) cw = 64;
            int col = 0;
            if (l < cw) col = edge_col[base + l];
            int nb = (cw + 15) >> 4;
            pad += (nb << 4) - cw;
            for (int b = 0; b < nb; ++b) {
                #pragma unroll
                for (int u = 0; u < 16; ++u) {
                    int idx = (b << 4) + u;
                    int c = __builtin_amdgcn_readlane(col, idx);
                    const float* rp = Hc + (size_t)c * D;   // uniform base -> saddr
                    float v = rp[l];
                    if (base + idx < eA) aA += v; else aB += v;   // uniform branch
                }
            }
            base += cw;
        }
        aB -= (float)pad * Hc[l];   // padding lanes gathered row 0 into the B side
        gvA = aA; gvB = aB;
    } else {
        int pr = (blockIdx.x - NODE_BLOCKS) * 8 + w;   // 0..31
        rA = 2 * pr; rB = rA + 1;                       // hs rows 0..63
        hvA = HSrw[(size_t)rA * D + l];
        hvB = HSrw[(size_t)rB * D + l];
        float aA = 0.f, aB = 0.f;
        #pragma unroll 4
        for (int c = 0; c < NCOPY; ++c) {
            float* pA = Pin + (size_t)c * (BATCH * D) + rA * D + l;
            float vA = pA[0], vB = pA[D];
            pA[0] = 0.f; pA[D] = 0.f;   // re-zero replicas for reuse
            aA += vA; aB += vB;
        }
        gvA = aA; gvB = aB;
    }

    // ---- dense: [hA|gA],[hB|gB] @ [M2;M3], LDS-broadcast, no readlanes ----
    sHG[w * 64 + l] = make_float4(hvA, hvB, gvA, gvB);
    float biasl = bl[l];
    float a2x = 0.f, a2y = 0.f, a3x = biasl, a3y = biasl;
    const float4* hg = &sHG[w * 64];
    #pragma unroll
    for (int kk = 0; kk < 32; ++kk) {
        float4 mm = sMM[kk * 64 + l];
        float4 h0 = hg[2 * kk];
        float4 h1 = hg[2 * kk + 1];
        a2x = fmaf(h0.x, mm.x, a2x); a2y = fmaf(h0.y, mm.x, a2y);
        a3x = fmaf(h0.z, mm.y, a3x); a3y = fmaf(h0.w, mm.y, a3y);
        a2x = fmaf(h1.x, mm.z, a2x); a2y = fmaf(h1.y, mm.z, a2y);
        a3x = fmaf(h1.z, mm.w, a3x); a3y = fmaf(h1.w, mm.w, a3y);
    }
    float vA = fmaxf(a2x + a3x, 0.f);
    float vB = fmaxf(a2y + a3y, 0.f);
    float ssA = vA * vA, ssB = vB * vB;
    #pragma unroll
    for (int off = 32; off; off >>= 1) {
        ssA += __shfl_xor(ssA, off);
        ssB += __shfl_xor(ssB, off);
    }
    float oA = vA / fmaxf(sqrtf(ssA), EPS);
    float oB = vB / fmaxf(sqrtf(ssB), EPS);

    if (is_node) {
        Hn[(size_t)rA * D + l] = oA;
        Hn[(size_t)rB * D + l] = oB;
        if (Pout) {
            int bA = rfl(batch[rA]);
            int bB = rfl(batch[rB]);
            float* cp = Pout + (size_t)(blockIdx.x & (NCOPY - 1)) * (BATCH * D);
            atomicAdd(&cp[bA * D + l], oA);
            atomicAdd(&cp[bB * D + l], oB);
        }
    } else {
        HSrw[(size_t)rA * D + l] = oA;
        HSrw[(size_t)rB * D + l] = oB;
    }
}

// ---------------------------------------------------------------------------
extern "C" void kernel_launch(void* const* d_in, const int* in_sizes, int n_in,
                              void* d_out, int out_size, void* d_ws, size_t ws_size,
                              hipStream_t stream) {
    const int*   edge_row = (const int*)  d_in[0];
    const int*   edge_col = (const int*)  d_in[1];
    const int*   batch    = (const int*)  d_in[2];
    const float* X        = (const float*)d_in[3];
    const float* Xs       = (const float*)d_in[4];
    const float* W1       = (const float*)d_in[5];
    const float* W2       = (const float*)d_in[6];
    const float* W3       = (const float*)d_in[7];
    const float* Wl       = (const float*)d_in[8];
    const float* bl       = (const float*)d_in[9];

    float* H  = (float*)d_out;                        // final node embeddings
    float* HS = (float*)d_out + (size_t)N_NODES * D;  // hs (updated in place)

    float* B0  = (float*)d_ws;                          // N_NODES*D
    float* B1  = B0 + (size_t)N_NODES * D;              // N_NODES*D
    float* PA  = B1 + (size_t)N_NODES * D;              // NCOPY*BATCH*D
    float* PB  = PA + (size_t)NCOPY * BATCH * D;        // NCOPY*BATCH*D
    float* MM4 = PB + (size_t)NCOPY * BATCH * D;        // 32*64*4 floats
    int*   row_start = (int*)(MM4 + 32 * 64 * 4);       // N_NODES+1

    k_prep<<<99, 512, 0, stream>>>(edge_row, row_start, PA, W2, W3, Wl, MM4);
    k_init<<<(N_NODES + BATCH + 3) / 4, 256, 0, stream>>>(X, Xs, W1, B0, HS, batch, PA);

    // iter 1: nodes h0(B0)->h1(B1), pool h1->PB ; hs uses pool(h0)=PA (zeroed after read)
    k_iter<<<ITER_GRID, 512, 0, stream>>>(edge_col, row_start, B0, B1, MM4, bl, batch, PB, HS, PA);
    // iter 2: nodes h1(B1)->h2(B0), pool h2->PA ; hs uses pool(h1)=PB
    k_iter<<<ITER_GRID, 512, 0, stream>>>(edge_col, row_start, B1, B0, MM4, bl, batch, PA, HS, PB);
    // iter 3: nodes h2(B0)->h3(H), no pool ; hs uses pool(h2)=PA
    k_iter<<<ITER_GRID, 512, 0, stream>>>(edge_col, row_start, B0, H, MM4, bl, batch, nullptr, HS, PA);
}